// Round 8
// baseline (304.347 us; speedup 1.0000x reference)
//
#include <hip/hip_runtime.h>
#include <hip/hip_bf16.h>

// Renderer vertex-normals rev8: f32 pipeline with EXPLICIT LHS-fma cross.
//   bs=32, V=65536, F=130050, C=6
// points:(bs,3,V) f32  faces:(F,3) i32  vti:(V,6) i32  vtw:(V,6,1) f32
// out:(bs,V,3) f32
//
// Forensics R0-R7: only the f32 fusion pattern of the cross product moves
// absmax (fused: 0.3496 / exact-zero degenerate: 0.4214). Reference must have
// nonzero fused-f32 garbage normals at the ~2 faces with i1==i2 (XLA
// contraction). f64 residuals are exactly 0 there (products of ~26-bit
// diffs fit in 53 bits) -> R7 == zero family. So: reproduce ref's pattern in
// f32 exactly. This rev: canonical LHS fusion, c_i = fmaf(a_p, b_q, -(a_q*b_p))
// with the unfused product pinned. Everything else plain f32 (bf16-invisible).

__device__ __forceinline__ float mulf_pin(float a, float b) {
  float t = a * b;
  asm("" : "+v"(t));   // pin: separately-rounded f32 product, cannot refuse
  return t;
}

__device__ __forceinline__ float3 cross_lhs(float ax, float ay, float az,
                                            float bx, float by, float bz) {
  // LHS pattern: fuse the FIRST product of each component.
  float cx = __builtin_fmaf(ay, bz, -mulf_pin(az, by));
  float cy = __builtin_fmaf(az, bx, -mulf_pin(ax, bz));
  float cz = __builtin_fmaf(ax, by, -mulf_pin(ay, bx));
  return make_float3(cx, cy, cz);
}

// ---------------- Pass A: face normals -> ws (float4 per (b,f)) ------------
__global__ __launch_bounds__(256) void rend8_face_pass(
    const float* __restrict__ points,
    const int*   __restrict__ faces,
    float4*      __restrict__ fnorm,
    int F, int V) {
  int f = blockIdx.x * blockDim.x + threadIdx.x;
  int b = blockIdx.y;
  if (f >= F) return;

  int i0 = faces[3 * f + 0];
  int i1 = faces[3 * f + 1];
  int i2 = faces[3 * f + 2];

  const float* pb = points + (size_t)b * 3 * V;
  float p0x = pb[i0], p0y = pb[V + i0], p0z = pb[2 * V + i0];
  float p1x = pb[i1], p1y = pb[V + i1], p1z = pb[2 * V + i1];
  float p2x = pb[i2], p2y = pb[V + i2], p2z = pb[2 * V + i2];

  float ax = p1x - p0x, ay = p1y - p0y, az = p1z - p0z;
  float bx = p2x - p0x, by = p2y - p0y, bz = p2z - p0z;

  float3 c = cross_lhs(ax, ay, az, bx, by, bz);

  float n2 = (c.x * c.x + c.y * c.y) + c.z * c.z;
  float n  = sqrtf(n2);
  float d  = fmaxf(n, 1e-12f);

  fnorm[(size_t)b * F + f] = make_float4(c.x / d, c.y / d, c.z / d, 0.0f);
}

// ---------------- Pass B: vertex normals -> out ----------------------------
__global__ __launch_bounds__(256) void rend8_vertex_pass(
    const float4* __restrict__ fnorm,
    const int*    __restrict__ vti,
    const float*  __restrict__ vtw,
    float*        __restrict__ out,
    int F, int V) {
  int v = blockIdx.x * blockDim.x + threadIdx.x;
  int b = blockIdx.y;
  if (v >= V) return;

  const float4* fb = fnorm + (size_t)b * F;

  float sx = 0.f, sy = 0.f, sz = 0.f;
#pragma unroll
  for (int c = 0; c < 6; ++c) {
    int    idx = vti[v * 6 + c];
    float  w   = vtw[v * 6 + c];
    float4 nr  = fb[idx];
    sx += nr.x * w;
    sy += nr.y * w;
    sz += nr.z * w;
  }

  float n = sqrtf((sx * sx + sy * sy) + sz * sz);
  float d = fmaxf(n, 1e-12f);

  size_t o = ((size_t)b * V + v) * 3;
  out[o + 0] = sx / d;
  out[o + 1] = sy / d;
  out[o + 2] = sz / d;
}

// ---------------- Fallback: fused, same math, no workspace -----------------
__global__ __launch_bounds__(256) void rend8_fused(
    const float* __restrict__ points,
    const int*   __restrict__ faces,
    const int*   __restrict__ vti,
    const float* __restrict__ vtw,
    float*       __restrict__ out,
    int F, int V) {
  int v = blockIdx.x * blockDim.x + threadIdx.x;
  int b = blockIdx.y;
  if (v >= V) return;

  const float* pb = points + (size_t)b * 3 * V;

  float sx = 0.f, sy = 0.f, sz = 0.f;
#pragma unroll
  for (int c = 0; c < 6; ++c) {
    int   f = vti[v * 6 + c];
    float w = vtw[v * 6 + c];
    int i0 = faces[3 * f + 0];
    int i1 = faces[3 * f + 1];
    int i2 = faces[3 * f + 2];

    float p0x = pb[i0], p0y = pb[V + i0], p0z = pb[2 * V + i0];
    float p1x = pb[i1], p1y = pb[V + i1], p1z = pb[2 * V + i1];
    float p2x = pb[i2], p2y = pb[V + i2], p2z = pb[2 * V + i2];

    float ax = p1x - p0x, ay = p1y - p0y, az = p1z - p0z;
    float bx = p2x - p0x, by = p2y - p0y, bz = p2z - p0z;

    float3 cr = cross_lhs(ax, ay, az, bx, by, bz);

    float n2 = (cr.x * cr.x + cr.y * cr.y) + cr.z * cr.z;
    float n  = sqrtf(n2);
    float d  = fmaxf(n, 1e-12f);

    sx += (cr.x / d) * w;
    sy += (cr.y / d) * w;
    sz += (cr.z / d) * w;
  }

  float n = sqrtf((sx * sx + sy * sy) + sz * sz);
  float d = fmaxf(n, 1e-12f);

  size_t o = ((size_t)b * V + v) * 3;
  out[o + 0] = sx / d;
  out[o + 1] = sy / d;
  out[o + 2] = sz / d;
}

extern "C" void kernel_launch(void* const* d_in, const int* in_sizes, int n_in,
                              void* d_out, int out_size, void* d_ws, size_t ws_size,
                              hipStream_t stream) {
  const float* points = (const float*)d_in[0];
  const int*   faces  = (const int*)d_in[1];
  const int*   vti    = (const int*)d_in[2];
  const float* vtw    = (const float*)d_in[3];
  float*       out    = (float*)d_out;

  const int F  = in_sizes[1] / 3;                       // 130050
  const int V  = in_sizes[2] / 6;                       // 65536
  const int bs = (int)(in_sizes[0] / (3 * (size_t)V));  // 32

  const size_t need = (size_t)bs * F * sizeof(float4);  // ~66.6 MB

  if (ws_size >= need) {
    float4* fnorm = (float4*)d_ws;
    dim3 gA((F + 255) / 256, bs);
    rend8_face_pass<<<gA, dim3(256), 0, stream>>>(points, faces, fnorm, F, V);
    dim3 gB((V + 255) / 256, bs);
    rend8_vertex_pass<<<gB, dim3(256), 0, stream>>>(fnorm, vti, vtw, out, F, V);
  } else {
    dim3 g((V + 255) / 256, bs);
    rend8_fused<<<g, dim3(256), 0, stream>>>(points, faces, vti, vtw, out, F, V);
  }
}

// Round 9
// 293.227 us; speedup vs baseline: 1.0379x; 1.0379x over previous
//
#include <hip/hip_runtime.h>
#include <hip/hip_bf16.h>

// Renderer vertex-normals rev9. Math is FROZEN from rev8 (first passing rev):
//   cross: c_i = fmaf(a_p, b_q, -pinned(a_q*b_p))  (uniform LHS fusion)
//   norms: (x*x + y*y) + z*z, sqrtf, fmaxf(n,1e-12f), IEEE '/'
//   vertex sum: c = 0..5 sequential
// Rev9 changes are layout/scheduling ONLY (bit-identical results):
//   A) pack points (bs,3,V) -> pts4 (bs,V) float4 xyz0: vertex gather = 1 line
//   B) face pass: indices loaded once, 8 batches per thread (batch-phase L2)
//   C) vertex pass: vti/vtw loaded once, 8 batches per thread
// bs=32, V=65536, F=130050, C=6.

#define NBG 4  // batch groups; BPG = bs/NBG batches per thread

__device__ __forceinline__ float mulf_pin(float a, float b) {
  float t = a * b;
  asm("" : "+v"(t));   // pin: separately-rounded f32 product, cannot re-fuse
  return t;
}

__device__ __forceinline__ float3 cross_lhs(float ax, float ay, float az,
                                            float bx, float by, float bz) {
  float cx = __builtin_fmaf(ay, bz, -mulf_pin(az, by));
  float cy = __builtin_fmaf(az, bx, -mulf_pin(ax, bz));
  float cz = __builtin_fmaf(ax, by, -mulf_pin(ay, bx));
  return make_float3(cx, cy, cz);
}

// ---------------- Kernel A: pack points into float4 (coalesced) ------------
__global__ __launch_bounds__(256) void rend9_pack(
    const float* __restrict__ points,   // (bs, 3, V)
    float4*      __restrict__ pts4,     // (bs, V)
    int V) {
  int v = blockIdx.x * blockDim.x + threadIdx.x;
  int b = blockIdx.y;
  const float* pb = points + (size_t)b * 3 * V;
  pts4[(size_t)b * V + v] = make_float4(pb[v], pb[V + v], pb[2 * V + v], 0.0f);
}

// ---------------- Kernel B: face normals, batched ---------------------------
__global__ __launch_bounds__(256) void rend9_face(
    const float4* __restrict__ pts4,    // (bs, V)
    const int*    __restrict__ faces,   // (F, 3)
    float4*       __restrict__ fnorm,   // (bs, F)
    int F, int V, int bs) {
  int f = blockIdx.x * blockDim.x + threadIdx.x;
  if (f >= F) return;

  int i0 = faces[3 * f + 0];
  int i1 = faces[3 * f + 1];
  int i2 = faces[3 * f + 2];

  int bpg = (bs + NBG - 1) / NBG;
  int b0  = blockIdx.y * bpg;
  int b1  = min(b0 + bpg, bs);

#pragma unroll 2
  for (int b = b0; b < b1; ++b) {
    const float4* P = pts4 + (size_t)b * V;
    float4 p0 = P[i0];
    float4 p1 = P[i1];
    float4 p2 = P[i2];

    float ax = p1.x - p0.x, ay = p1.y - p0.y, az = p1.z - p0.z;
    float bx = p2.x - p0.x, by = p2.y - p0.y, bz = p2.z - p0.z;

    float3 c = cross_lhs(ax, ay, az, bx, by, bz);

    float n2 = (c.x * c.x + c.y * c.y) + c.z * c.z;
    float n  = sqrtf(n2);
    float d  = fmaxf(n, 1e-12f);

    fnorm[(size_t)b * F + f] = make_float4(c.x / d, c.y / d, c.z / d, 0.0f);
  }
}

// ---------------- Kernel C: vertex normals, batched -------------------------
__global__ __launch_bounds__(256) void rend9_vertex(
    const float4* __restrict__ fnorm,   // (bs, F)
    const int*    __restrict__ vti,     // (V, 6)
    const float*  __restrict__ vtw,     // (V, 6)
    float*        __restrict__ out,     // (bs, V, 3)
    int F, int V, int bs) {
  int v = blockIdx.x * blockDim.x + threadIdx.x;
  if (v >= V) return;

  // vti/vtw rows are 24 B, 8-aligned -> three 8 B loads each.
  const int2*   t2 = (const int2*)(vti + (size_t)v * 6);
  const float2* w2 = (const float2*)(vtw + (size_t)v * 6);
  int2   t01 = t2[0], t23 = t2[1], t45 = t2[2];
  float2 w01 = w2[0], w23 = w2[1], w45 = w2[2];
  int   idx[6] = {t01.x, t01.y, t23.x, t23.y, t45.x, t45.y};
  float wgt[6] = {w01.x, w01.y, w23.x, w23.y, w45.x, w45.y};

  int bpg = (bs + NBG - 1) / NBG;
  int b0  = blockIdx.y * bpg;
  int b1  = min(b0 + bpg, bs);

#pragma unroll 2
  for (int b = b0; b < b1; ++b) {
    const float4* FN = fnorm + (size_t)b * F;

    float sx = 0.f, sy = 0.f, sz = 0.f;
#pragma unroll
    for (int c = 0; c < 6; ++c) {          // sequential c-order (frozen)
      float4 nr = FN[idx[c]];
      sx += nr.x * wgt[c];
      sy += nr.y * wgt[c];
      sz += nr.z * wgt[c];
    }

    float n = sqrtf((sx * sx + sy * sy) + sz * sz);
    float d = fmaxf(n, 1e-12f);

    size_t o = ((size_t)b * V + v) * 3;
    out[o + 0] = sx / d;
    out[o + 1] = sy / d;
    out[o + 2] = sz / d;
  }
}

// ================= Fallback path (rev8, proven): ===========================
__global__ __launch_bounds__(256) void rend9_face_fb(
    const float* __restrict__ points,
    const int*   __restrict__ faces,
    float4*      __restrict__ fnorm,
    int F, int V) {
  int f = blockIdx.x * blockDim.x + threadIdx.x;
  int b = blockIdx.y;
  if (f >= F) return;

  int i0 = faces[3 * f + 0];
  int i1 = faces[3 * f + 1];
  int i2 = faces[3 * f + 2];

  const float* pb = points + (size_t)b * 3 * V;
  float ax = pb[i1] - pb[i0], ay = pb[V + i1] - pb[V + i0], az = pb[2 * V + i1] - pb[2 * V + i0];
  float bx = pb[i2] - pb[i0], by = pb[V + i2] - pb[V + i0], bz = pb[2 * V + i2] - pb[2 * V + i0];

  float3 c = cross_lhs(ax, ay, az, bx, by, bz);

  float n = sqrtf((c.x * c.x + c.y * c.y) + c.z * c.z);
  float d = fmaxf(n, 1e-12f);

  fnorm[(size_t)b * F + f] = make_float4(c.x / d, c.y / d, c.z / d, 0.0f);
}

__global__ __launch_bounds__(256) void rend9_vertex_fb(
    const float4* __restrict__ fnorm,
    const int*    __restrict__ vti,
    const float*  __restrict__ vtw,
    float*        __restrict__ out,
    int F, int V) {
  int v = blockIdx.x * blockDim.x + threadIdx.x;
  int b = blockIdx.y;
  if (v >= V) return;

  const float4* fb = fnorm + (size_t)b * F;
  float sx = 0.f, sy = 0.f, sz = 0.f;
#pragma unroll
  for (int c = 0; c < 6; ++c) {
    int    idx = vti[v * 6 + c];
    float  w   = vtw[v * 6 + c];
    float4 nr  = fb[idx];
    sx += nr.x * w;
    sy += nr.y * w;
    sz += nr.z * w;
  }
  float n = sqrtf((sx * sx + sy * sy) + sz * sz);
  float d = fmaxf(n, 1e-12f);
  size_t o = ((size_t)b * V + v) * 3;
  out[o + 0] = sx / d;
  out[o + 1] = sy / d;
  out[o + 2] = sz / d;
}

extern "C" void kernel_launch(void* const* d_in, const int* in_sizes, int n_in,
                              void* d_out, int out_size, void* d_ws, size_t ws_size,
                              hipStream_t stream) {
  const float* points = (const float*)d_in[0];
  const int*   faces  = (const int*)d_in[1];
  const int*   vti    = (const int*)d_in[2];
  const float* vtw    = (const float*)d_in[3];
  float*       out    = (float*)d_out;

  const int F  = in_sizes[1] / 3;                       // 130050
  const int V  = in_sizes[2] / 6;                       // 65536
  const int bs = (int)(in_sizes[0] / (3 * (size_t)V));  // 32

  const size_t pts4_bytes = (size_t)bs * V * sizeof(float4);  // 33.6 MB
  const size_t fn_bytes   = (size_t)bs * F * sizeof(float4);  // 66.6 MB

  if (ws_size >= pts4_bytes + fn_bytes) {
    float4* pts4  = (float4*)d_ws;
    float4* fnorm = (float4*)((char*)d_ws + pts4_bytes);

    rend9_pack<<<dim3(V / 256, bs), dim3(256), 0, stream>>>(points, pts4, V);
    rend9_face<<<dim3((F + 255) / 256, NBG), dim3(256), 0, stream>>>(
        pts4, faces, fnorm, F, V, bs);
    rend9_vertex<<<dim3((V + 255) / 256, NBG), dim3(256), 0, stream>>>(
        fnorm, vti, vtw, out, F, V, bs);
  } else {  // rev8 fallback (needs only fn table)
    float4* fnorm = (float4*)d_ws;
    rend9_face_fb<<<dim3((F + 255) / 256, bs), dim3(256), 0, stream>>>(
        points, faces, fnorm, F, V);
    rend9_vertex_fb<<<dim3((V + 255) / 256, bs), dim3(256), 0, stream>>>(
        fnorm, vti, vtw, out, F, V);
  }
}

// Round 10
// 221.976 us; speedup vs baseline: 1.3711x; 1.3210x over previous
//
#include <hip/hip_runtime.h>
#include <hip/hip_bf16.h>

// Renderer vertex-normals rev10. Math FROZEN from rev8 (passing, absmax = 1 bf16 ulp):
//   cross: c_i = fmaf(a_p, b_q, -pinned(a_q*b_p))  (uniform LHS fusion)
//   norms: (x*x + y*y) + z*z, sqrtf, fmaxf(n,1e-12f), IEEE '/'
//   vertex sum: c = 0..5 sequential
// Rev10 = XCD-partitioned batch scheduling (layout/scheduling only):
//   blockIdx.x % 8 ~ XCD (round-robin dispatch). Each XCD owns bs/8 = 4
//   batches; its 2 MB fn / 1 MB pts4 tables stay hot in its private 4 MB L2.
//   R9 thrashed: 4 batch-groups interleaved on every XCD -> 452 MB FETCH in
//   the vertex pass (vs ~95 MB compulsory).
// bs=32, V=65536, F=130050, C=6.

#define XCDS 8

__device__ __forceinline__ float mulf_pin(float a, float b) {
  float t = a * b;
  asm("" : "+v"(t));   // pin: separately-rounded f32 product, cannot re-fuse
  return t;
}

__device__ __forceinline__ float3 cross_lhs(float ax, float ay, float az,
                                            float bx, float by, float bz) {
  float cx = __builtin_fmaf(ay, bz, -mulf_pin(az, by));
  float cy = __builtin_fmaf(az, bx, -mulf_pin(ax, bz));
  float cz = __builtin_fmaf(ax, by, -mulf_pin(ay, bx));
  return make_float3(cx, cy, cz);
}

// ---------------- Kernel A: pack points into float4 (coalesced) ------------
__global__ __launch_bounds__(256) void rend10_pack(
    const float* __restrict__ points,   // (bs, 3, V)
    float4*      __restrict__ pts4,     // (bs, V)
    int V) {
  int v = blockIdx.x * blockDim.x + threadIdx.x;
  int b = blockIdx.y;
  const float* pb = points + (size_t)b * 3 * V;
  pts4[(size_t)b * V + v] = make_float4(pb[v], pb[V + v], pb[2 * V + v], 0.0f);
}

// ---------------- Kernel B: face normals, XCD-partitioned ------------------
// grid.x = XCDS * (bs/XCDS) * fpb ; seq ordered batch-major within an XCD so
// resident blocks stay within ~1 pts4 table.
__global__ __launch_bounds__(256) void rend10_face(
    const float4* __restrict__ pts4,    // (bs, V)
    const int*    __restrict__ faces,   // (F, 3)
    float4*       __restrict__ fnorm,   // (bs, F)
    int F, int V, int bpx, int fpb) {   // bpx = bs/XCDS, fpb = face-blocks/batch
  int xcd = blockIdx.x % XCDS;
  int seq = blockIdx.x / XCDS;
  int bl  = seq / fpb;
  int fb  = seq - bl * fpb;
  int f   = fb * 256 + threadIdx.x;
  if (f >= F) return;
  int b   = xcd * bpx + bl;

  int i0 = faces[3 * f + 0];
  int i1 = faces[3 * f + 1];
  int i2 = faces[3 * f + 2];

  const float4* P = pts4 + (size_t)b * V;
  float4 p0 = P[i0];
  float4 p1 = P[i1];
  float4 p2 = P[i2];

  float ax = p1.x - p0.x, ay = p1.y - p0.y, az = p1.z - p0.z;
  float bx = p2.x - p0.x, by = p2.y - p0.y, bz = p2.z - p0.z;

  float3 c = cross_lhs(ax, ay, az, bx, by, bz);

  float n = sqrtf((c.x * c.x + c.y * c.y) + c.z * c.z);
  float d = fmaxf(n, 1e-12f);

  fnorm[(size_t)b * F + f] = make_float4(c.x / d, c.y / d, c.z / d, 0.0f);
}

// ---------------- Kernel C: vertex normals, XCD-partitioned ----------------
// grid.x = XCDS * ceil(V/256). Thread loads vti/vtw once, loops its XCD's
// bpx batches; all blocks co-resident -> tables swept in phase.
__global__ __launch_bounds__(256) void rend10_vertex(
    const float4* __restrict__ fnorm,   // (bs, F)
    const int*    __restrict__ vti,     // (V, 6)
    const float*  __restrict__ vtw,     // (V, 6)
    float*        __restrict__ out,     // (bs, V, 3)
    int F, int V, int bpx) {
  int xcd = blockIdx.x % XCDS;
  int seq = blockIdx.x / XCDS;
  int v   = seq * 256 + threadIdx.x;
  if (v >= V) return;

  const int2*   t2 = (const int2*)(vti + (size_t)v * 6);
  const float2* w2 = (const float2*)(vtw + (size_t)v * 6);
  int2   t01 = t2[0], t23 = t2[1], t45 = t2[2];
  float2 w01 = w2[0], w23 = w2[1], w45 = w2[2];
  int   idx[6] = {t01.x, t01.y, t23.x, t23.y, t45.x, t45.y};
  float wgt[6] = {w01.x, w01.y, w23.x, w23.y, w45.x, w45.y};

  for (int bl = 0; bl < bpx; ++bl) {
    int b = xcd * bpx + bl;
    const float4* FN = fnorm + (size_t)b * F;

    float sx = 0.f, sy = 0.f, sz = 0.f;
#pragma unroll
    for (int c = 0; c < 6; ++c) {          // sequential c-order (frozen)
      float4 nr = FN[idx[c]];
      sx += nr.x * wgt[c];
      sy += nr.y * wgt[c];
      sz += nr.z * wgt[c];
    }

    float n = sqrtf((sx * sx + sy * sy) + sz * sz);
    float d = fmaxf(n, 1e-12f);

    size_t o = ((size_t)b * V + v) * 3;
    out[o + 0] = sx / d;
    out[o + 1] = sy / d;
    out[o + 2] = sz / d;
  }
}

// ================= Fallback path (rev8, proven): ===========================
__global__ __launch_bounds__(256) void rend10_face_fb(
    const float* __restrict__ points,
    const int*   __restrict__ faces,
    float4*      __restrict__ fnorm,
    int F, int V) {
  int f = blockIdx.x * blockDim.x + threadIdx.x;
  int b = blockIdx.y;
  if (f >= F) return;

  int i0 = faces[3 * f + 0];
  int i1 = faces[3 * f + 1];
  int i2 = faces[3 * f + 2];

  const float* pb = points + (size_t)b * 3 * V;
  float ax = pb[i1] - pb[i0], ay = pb[V + i1] - pb[V + i0], az = pb[2 * V + i1] - pb[2 * V + i0];
  float bx = pb[i2] - pb[i0], by = pb[V + i2] - pb[V + i0], bz = pb[2 * V + i2] - pb[2 * V + i0];

  float3 c = cross_lhs(ax, ay, az, bx, by, bz);

  float n = sqrtf((c.x * c.x + c.y * c.y) + c.z * c.z);
  float d = fmaxf(n, 1e-12f);

  fnorm[(size_t)b * F + f] = make_float4(c.x / d, c.y / d, c.z / d, 0.0f);
}

__global__ __launch_bounds__(256) void rend10_vertex_fb(
    const float4* __restrict__ fnorm,
    const int*    __restrict__ vti,
    const float*  __restrict__ vtw,
    float*        __restrict__ out,
    int F, int V) {
  int v = blockIdx.x * blockDim.x + threadIdx.x;
  int b = blockIdx.y;
  if (v >= V) return;

  const float4* fb = fnorm + (size_t)b * F;
  float sx = 0.f, sy = 0.f, sz = 0.f;
#pragma unroll
  for (int c = 0; c < 6; ++c) {
    int    idx = vti[v * 6 + c];
    float  w   = vtw[v * 6 + c];
    float4 nr  = fb[idx];
    sx += nr.x * w;
    sy += nr.y * w;
    sz += nr.z * w;
  }
  float n = sqrtf((sx * sx + sy * sy) + sz * sz);
  float d = fmaxf(n, 1e-12f);
  size_t o = ((size_t)b * V + v) * 3;
  out[o + 0] = sx / d;
  out[o + 1] = sy / d;
  out[o + 2] = sz / d;
}

extern "C" void kernel_launch(void* const* d_in, const int* in_sizes, int n_in,
                              void* d_out, int out_size, void* d_ws, size_t ws_size,
                              hipStream_t stream) {
  const float* points = (const float*)d_in[0];
  const int*   faces  = (const int*)d_in[1];
  const int*   vti    = (const int*)d_in[2];
  const float* vtw    = (const float*)d_in[3];
  float*       out    = (float*)d_out;

  const int F  = in_sizes[1] / 3;                       // 130050
  const int V  = in_sizes[2] / 6;                       // 65536
  const int bs = (int)(in_sizes[0] / (3 * (size_t)V));  // 32

  const size_t pts4_bytes = (size_t)bs * V * sizeof(float4);  // 33.6 MB
  const size_t fn_bytes   = (size_t)bs * F * sizeof(float4);  // 66.6 MB

  const bool fast_ok = (ws_size >= pts4_bytes + fn_bytes) &&
                       (bs % XCDS == 0) && (V % 256 == 0);

  if (fast_ok) {
    float4* pts4  = (float4*)d_ws;
    float4* fnorm = (float4*)((char*)d_ws + pts4_bytes);
    const int bpx = bs / XCDS;                 // 4 batches per XCD
    const int fpb = (F + 255) / 256;           // 509 face-blocks per batch
    const int vpb = V / 256;                   // 256 vertex-blocks

    rend10_pack<<<dim3(V / 256, bs), dim3(256), 0, stream>>>(points, pts4, V);
    rend10_face<<<dim3(XCDS * bpx * fpb), dim3(256), 0, stream>>>(
        pts4, faces, fnorm, F, V, bpx, fpb);
    rend10_vertex<<<dim3(XCDS * vpb), dim3(256), 0, stream>>>(
        fnorm, vti, vtw, out, F, V, bpx);
  } else if (ws_size >= fn_bytes) {  // rev8 fallback
    float4* fnorm = (float4*)d_ws;
    rend10_face_fb<<<dim3((F + 255) / 256, bs), dim3(256), 0, stream>>>(
        points, faces, fnorm, F, V);
    rend10_vertex_fb<<<dim3((V + 255) / 256, bs), dim3(256), 0, stream>>>(
        fnorm, vti, vtw, out, F, V);
  }
}